// Round 4
// baseline (120.933 us; speedup 1.0000x reference)
//
#include <hip/hip_runtime.h>

#define E_DIM 256
#define S_DIM 2048
#define B_DIM 8

typedef unsigned short u16;
typedef __bf16 bf16x8 __attribute__((ext_vector_type(8)));
typedef float f32x4 __attribute__((ext_vector_type(4)));
typedef u16 u16x8 __attribute__((ext_vector_type(8)));

__device__ inline u16 f2bf(float f) {
  unsigned u = __builtin_bit_cast(unsigned, f);
  return (u16)((u + 0x7FFF + ((u >> 16) & 1)) >> 16);  // RTNE, finite inputs
}
__device__ inline float bf2f(u16 v) {
  unsigned u = ((unsigned)v) << 16;
  return __builtin_bit_cast(float, u);
}

// ---------------------------------------------------------------------------
// Prep: Wq, Wo (fp32 [f][e]) -> bf16 [f][e]
// ---------------------------------------------------------------------------
__global__ __launch_bounds__(256) void convert_w(
    const float* __restrict__ Wq, const float* __restrict__ Wo,
    u16* __restrict__ Wqb, u16* __restrict__ Wob) {
  int idx = (blockIdx.x * 256 + threadIdx.x) * 4;  // grid 128 -> 131072 elems
  const float* src;
  u16* dst;
  if (idx < 65536) { src = Wq + idx; dst = Wqb + idx; }
  else { src = Wo + (idx - 65536); dst = Wob + (idx - 65536); }
  float4 v = *(const float4*)src;
  ushort4 o = make_ushort4(f2bf(v.x), f2bf(v.y), f2bf(v.z), f2bf(v.w));
  *(ushort4*)dst = o;
}

// ---------------------------------------------------------------------------
// Fused kernel: one block = (b, 16-s tile); 1024 blocks = 4/CU (16 waves/CU).
//  P0: stage xt[r][e] bf16, r=0..31 (t = s0-4+r; r>=24 or OOB -> 0)
//  P1: q = xt . Wq^T + bq (MFMA, M=32 N=256 K=256) -> qt bf16 rows 0..23
//  P2: banded energies from qt, cross-wave reduce, softmax -> ldsw[16][9]
//  P3: pooled[s][e] = sum_l w[s][l] * xt[s+l][e]  (bf16, aliases qt)
//  P4: out[b][f][s] = (pooled . Wo^T + bo)/9 (MFMA, M=16 N=256 K=256)
// Zero-staged OOB rows make q_row = bq exactly (reference padding semantics)
// and give zero-padded pooling for free.
// ---------------------------------------------------------------------------
#define TS 16
#define QR 24      // valid staged q rows: t = s0-4 .. s0+19
#define XROWS 32   // padded to 2 m-frags of 16
#define XSTR 264   // u16 row stride
#define QSTR 266   // u16 (odd dword stride: banded scalar reads conflict-free)
#define PSTR 264

__global__ __launch_bounds__(256) void fused_attn(
    const float* __restrict__ x, const u16* __restrict__ Wqb,
    const float* __restrict__ bq, const u16* __restrict__ Wob,
    const float* __restrict__ bo, float* __restrict__ out) {
  // LDS: xt 16896 | qt 12768 (pooled 8448 aliases) | part2 2304 | ldsw 576
  __shared__ __align__(16) char smem[32544];
  u16* xt = (u16*)smem;
  u16* qt = (u16*)(smem + 16896);
  u16* pooled = qt;
  float* part2 = (float*)(smem + 29664);  // [4][TS][9]
  float* ldsw = (float*)(smem + 31968);   // [TS][9]

  const int tid = threadIdx.x;
  const int s0 = blockIdx.x * TS;
  const int b = blockIdx.y;
  const int wave = tid >> 6, lane = tid & 63;
  const int lm = lane & 15, lk = lane >> 4;

  // ---- P0: stage xt. r=lane&31, e-half=lane>>5: all 64 lanes active;
  //      per-load lanes read 32 consecutive t at fixed e (2x128B segments).
  {
    const int r = lane & 31;
    const int h = lane >> 5;
    const int t = s0 - 4 + r;
    const bool v = (r < QR) && (t >= 0) && (t < S_DIM);
    const int ebase = wave * 64 + h * 32;
    const float* __restrict__ xb = x + (size_t)b * E_DIM * S_DIM + t;
#pragma unroll
    for (int c = 0; c < 4; ++c) {
      u16x8 v8;
#pragma unroll
      for (int u = 0; u < 8; ++u) {
        int e = ebase + c * 8 + u;
        float xv = v ? xb[(size_t)e * S_DIM] : 0.f;
        v8[u] = f2bf(xv);
      }
      *(u16x8*)&xt[r * XSTR + ebase + c * 8] = v8;
    }
  }
  __syncthreads();

  // ---- P1: K1 MFMA -> qt (rows 0..23) ----
  {
    const f32x4 zero = {0.f, 0.f, 0.f, 0.f};
    f32x4 acc[2][4];
#pragma unroll
    for (int i = 0; i < 2; ++i)
#pragma unroll
      for (int j = 0; j < 4; ++j) acc[i][j] = zero;
#pragma unroll
    for (int k0 = 0; k0 < 8; ++k0) {
      bf16x8 af[2], bf[4];
#pragma unroll
      for (int i = 0; i < 2; ++i)
        af[i] = *(const bf16x8*)&xt[(i * 16 + lm) * XSTR + k0 * 32 + lk * 8];
#pragma unroll
      for (int j = 0; j < 4; ++j)
        bf[j] = *(const bf16x8*)&Wqb[(size_t)(wave * 64 + j * 16 + lm) * E_DIM +
                                     k0 * 32 + lk * 8];
#pragma unroll
      for (int i = 0; i < 2; ++i)
#pragma unroll
        for (int j = 0; j < 4; ++j)
          acc[i][j] = __builtin_amdgcn_mfma_f32_16x16x32_bf16(af[i], bf[j], acc[i][j], 0, 0, 0);
    }
#pragma unroll
    for (int j = 0; j < 4; ++j) {
      int f = wave * 64 + j * 16 + lm;
      float bv = bq[f];
#pragma unroll
      for (int i = 0; i < 2; ++i) {
        int row = i * 16 + lk * 4;
#pragma unroll
        for (int r2 = 0; r2 < 4; ++r2)
          if (row + r2 < QR) qt[(row + r2) * QSTR + f] = f2bf(acc[i][j][r2] + bv);
      }
    }
  }
  __syncthreads();

  // ---- P2: banded energies + softmax ----
  {
    const int a = tid & 7;     // s = 2a+si, si<2
    const int fpg = tid >> 3;  // 0..31
    float accE[2][9];
#pragma unroll
    for (int si = 0; si < 2; ++si)
#pragma unroll
      for (int l = 0; l < 9; ++l) accE[si][l] = 0.f;
    for (int j = 0; j < 8; ++j) {
      int f = fpg + 32 * j;
      float rr[10];
#pragma unroll
      for (int i = 0; i < 10; ++i) rr[i] = bf2f(qt[(2 * a + i) * QSTR + f]);
#pragma unroll
      for (int si = 0; si < 2; ++si) {
        float c = rr[si + 4];
#pragma unroll
        for (int l = 0; l < 9; ++l) accE[si][l] += c * rr[si + l];
      }
    }
#pragma unroll
    for (int off = 8; off < 64; off <<= 1)
#pragma unroll
      for (int si = 0; si < 2; ++si)
#pragma unroll
        for (int l = 0; l < 9; ++l) accE[si][l] += __shfl_xor(accE[si][l], off, 64);
    if (lane < 8)
#pragma unroll
      for (int si = 0; si < 2; ++si)
#pragma unroll
        for (int l = 0; l < 9; ++l)
          part2[(wave * TS + 2 * a + si) * 9 + l] = accE[si][l];
  }
  __syncthreads();
  if (tid < TS) {
    float e[9];
#pragma unroll
    for (int l = 0; l < 9; ++l)
      e[l] = (part2[(0 * TS + tid) * 9 + l] + part2[(1 * TS + tid) * 9 + l] +
              part2[(2 * TS + tid) * 9 + l] + part2[(3 * TS + tid) * 9 + l]) *
             (1.0f / 24.0f);
    float m = e[0];
#pragma unroll
    for (int l = 1; l < 9; ++l) m = fmaxf(m, e[l]);
    float s = 0.f;
#pragma unroll
    for (int l = 0; l < 9; ++l) {
      e[l] = __expf(e[l] - m);
      s += e[l];
    }
    float inv = 1.0f / s;
#pragma unroll
    for (int l = 0; l < 9; ++l) ldsw[tid * 9 + l] = e[l] * inv;
  }
  __syncthreads();

  // ---- P3: pooled[s][e] = sum_l w[s][l] * xt[s+l][e]  (overlays qt) ----
  {
    const int s = tid & 15, ep = tid >> 4;  // ep 0..15, 16 e each
    float w9[9];
#pragma unroll
    for (int l = 0; l < 9; ++l) w9[l] = ldsw[s * 9 + l];
#pragma unroll
    for (int c = 0; c < 2; ++c) {
      int e8 = ep * 16 + c * 8;
      float o[8];
#pragma unroll
      for (int u = 0; u < 8; ++u) o[u] = 0.f;
#pragma unroll
      for (int l = 0; l < 9; ++l) {
        u16x8 xv = *(const u16x8*)&xt[(s + l) * XSTR + e8];
#pragma unroll
        for (int u = 0; u < 8; ++u) o[u] += w9[l] * bf2f(xv[u]);
      }
      u16x8 pv;
#pragma unroll
      for (int u = 0; u < 8; ++u) pv[u] = f2bf(o[u]);
      *(u16x8*)&pooled[s * PSTR + e8] = pv;
    }
  }
  __syncthreads();

  // ---- P4: K3 MFMA -> out[b][f][s] ----
  {
    const f32x4 zero = {0.f, 0.f, 0.f, 0.f};
    f32x4 acc[4];
#pragma unroll
    for (int j = 0; j < 4; ++j) acc[j] = zero;
#pragma unroll
    for (int k0 = 0; k0 < 8; ++k0) {
      bf16x8 af, bf[4];
      af = *(const bf16x8*)&pooled[lm * PSTR + k0 * 32 + lk * 8];
#pragma unroll
      for (int j = 0; j < 4; ++j)
        bf[j] = *(const bf16x8*)&Wob[(size_t)(wave * 64 + j * 16 + lm) * E_DIM +
                                     k0 * 32 + lk * 8];
#pragma unroll
      for (int j = 0; j < 4; ++j)
        acc[j] = __builtin_amdgcn_mfma_f32_16x16x32_bf16(af, bf[j], acc[j], 0, 0, 0);
    }
#pragma unroll
    for (int j = 0; j < 4; ++j) {
      int f = wave * 64 + j * 16 + lm;
      float bv = bo[f];
      int sl = lk * 4;
      float4 w = make_float4((acc[j][0] + bv) * (1.0f / 9.0f),
                             (acc[j][1] + bv) * (1.0f / 9.0f),
                             (acc[j][2] + bv) * (1.0f / 9.0f),
                             (acc[j][3] + bv) * (1.0f / 9.0f));
      *(float4*)&out[((size_t)b * E_DIM + f) * S_DIM + s0 + sl] = w;
    }
  }
}

// ---------------------------------------------------------------------------
extern "C" void kernel_launch(void* const* d_in, const int* in_sizes, int n_in,
                              void* d_out, int out_size, void* d_ws, size_t ws_size,
                              hipStream_t stream) {
  const float* x = (const float*)d_in[0];
  const float* Wq = (const float*)d_in[1];
  const float* bq = (const float*)d_in[2];
  const float* Wo = (const float*)d_in[3];
  const float* bo = (const float*)d_in[4];
  float* out = (float*)d_out;

  u16* Wqb = (u16*)d_ws;
  u16* Wob = Wqb + 65536;

  convert_w<<<128, 256, 0, stream>>>(Wq, Wo, Wqb, Wob);
  fused_attn<<<dim3(S_DIM / TS, B_DIM), 256, 0, stream>>>(x, Wqb, bq, Wob, bo, out);
}

// Round 5
// 102.500 us; speedup vs baseline: 1.1798x; 1.1798x over previous
//
#include <hip/hip_runtime.h>

#define E_DIM 256
#define S_DIM 2048
#define B_DIM 8

typedef unsigned short u16;
typedef __bf16 bf16x8 __attribute__((ext_vector_type(8)));
typedef float f32x4 __attribute__((ext_vector_type(4)));
typedef u16 u16x8 __attribute__((ext_vector_type(8)));

__device__ inline u16 f2bf(float f) {
  unsigned u = __builtin_bit_cast(unsigned, f);
  return (u16)((u + 0x7FFF + ((u >> 16) & 1)) >> 16);  // RTNE, finite inputs
}
__device__ inline float bf2f(u16 v) {
  unsigned u = ((unsigned)v) << 16;
  return __builtin_bit_cast(float, u);
}

// ---------------------------------------------------------------------------
// Prep: Wq, Wo (fp32 [f][e]) -> bf16 [f][e]
// ---------------------------------------------------------------------------
__global__ __launch_bounds__(256) void convert_w(
    const float* __restrict__ Wq, const float* __restrict__ Wo,
    u16* __restrict__ Wqb, u16* __restrict__ Wob) {
  int idx = (blockIdx.x * 256 + threadIdx.x) * 4;  // grid 128 -> 131072 elems
  const float* src;
  u16* dst;
  if (idx < 65536) { src = Wq + idx; dst = Wqb + idx; }
  else { src = Wo + (idx - 65536); dst = Wob + (idx - 65536); }
  float4 v = *(const float4*)src;
  ushort4 o = make_ushort4(f2bf(v.x), f2bf(v.y), f2bf(v.z), f2bf(v.w));
  *(ushort4*)dst = o;
}

// ---------------------------------------------------------------------------
// Fused kernel: one block = (b, 32-s tile), 512 threads (8 waves).
// Grid 512 = 2 blocks/CU (16 waves/CU).
//  P0: stage xt[r][e] bf16, r=0..47 (t = s0-4+r; r>=40 or OOB -> 0)
//  P1: q = xt . Wq^T + bq (MFMA, M=48 N=256 K=256) -> qt bf16 rows 0..39
//  P2: banded energies from qt, cross-wave reduce, softmax -> ldsw[32][9]
//  P3: pooled[s][e] = sum_l w[s][l] * xt[s+l][e]  (bf16, aliases qt)
//  P4: out[b][f][s] = (pooled . Wo^T + bo)/9 (MFMA, M=32 N=256 K=256)
// Zero-staged OOB rows make q_row = bq exactly (reference padding semantics)
// and give zero-padded pooling for free.
// ---------------------------------------------------------------------------
#define TS 32
#define QR 40      // valid staged q rows: t = s0-4 .. s0+35
#define XROWS 48   // padded to 3 m-frags of 16
#define XSTR 264   // u16 row stride (132 dw: b128 dense-pack conflict-free)
#define QSTR 266   // u16 (133 dw odd: banded scalar reads conflict-free)
#define PSTR 264

__global__ __launch_bounds__(512) void fused_attn(
    const float* __restrict__ x, const u16* __restrict__ Wqb,
    const float* __restrict__ bq, const u16* __restrict__ Wob,
    const float* __restrict__ bo, float* __restrict__ out) {
  // LDS: xt 25344 | qt 21280 (pooled 16896 aliases) | part2 9216 | ldsw 1152
  __shared__ __align__(16) char smem[56992];
  u16* xt = (u16*)smem;
  u16* qt = (u16*)(smem + 25344);
  u16* pooled = qt;
  float* part2 = (float*)(smem + 46624);  // [8][TS][9]
  float* ldsw = (float*)(smem + 55840);   // [TS][9]

  const int tid = threadIdx.x;
  const int s0 = blockIdx.x * TS;
  const int b = blockIdx.y;
  const int wave = tid >> 6, lane = tid & 63;
  const int lm = lane & 15, lk = lane >> 4;

  // ---- P0: stage xt. lane = row (valid < 48), wave = 32-e slice;
  //      per load, lanes span consecutive t (coalesced 128B+ segments).
  {
    const int r = lane;
    const int t = s0 - 4 + r;
    const bool v = (r < QR) && (t >= 0) && (t < S_DIM);
    if (r < XROWS) {
      const float* __restrict__ xb = x + (size_t)b * E_DIM * S_DIM + t;
      const int ebase = wave * 32;
#pragma unroll
      for (int c = 0; c < 4; ++c) {
        u16x8 v8;
#pragma unroll
        for (int u = 0; u < 8; ++u) {
          int e = ebase + c * 8 + u;
          float xv = v ? xb[(size_t)e * S_DIM] : 0.f;
          v8[u] = f2bf(xv);
        }
        *(u16x8*)&xt[r * XSTR + ebase + c * 8] = v8;
      }
    }
  }
  __syncthreads();

  // ---- P1: K1 MFMA -> qt (rows 0..39). Wave covers f-range wave*32, j<2.
  {
    const f32x4 zero = {0.f, 0.f, 0.f, 0.f};
    f32x4 acc[3][2];
#pragma unroll
    for (int i = 0; i < 3; ++i)
#pragma unroll
      for (int j = 0; j < 2; ++j) acc[i][j] = zero;
#pragma unroll
    for (int k0 = 0; k0 < 8; ++k0) {
      bf16x8 af[3], bf[2];
#pragma unroll
      for (int i = 0; i < 3; ++i)
        af[i] = *(const bf16x8*)&xt[(i * 16 + lm) * XSTR + k0 * 32 + lk * 8];
#pragma unroll
      for (int j = 0; j < 2; ++j)
        bf[j] = *(const bf16x8*)&Wqb[(size_t)(wave * 32 + j * 16 + lm) * E_DIM +
                                     k0 * 32 + lk * 8];
#pragma unroll
      for (int i = 0; i < 3; ++i)
#pragma unroll
        for (int j = 0; j < 2; ++j)
          acc[i][j] = __builtin_amdgcn_mfma_f32_16x16x32_bf16(af[i], bf[j], acc[i][j], 0, 0, 0);
    }
#pragma unroll
    for (int j = 0; j < 2; ++j) {
      int f = wave * 32 + j * 16 + lm;
      float bv = bq[f];
#pragma unroll
      for (int i = 0; i < 3; ++i) {
        int row = i * 16 + lk * 4;
#pragma unroll
        for (int r2 = 0; r2 < 4; ++r2)
          if (row + r2 < QR) qt[(row + r2) * QSTR + f] = f2bf(acc[i][j][r2] + bv);
      }
    }
  }
  __syncthreads();

  // ---- P2: banded energies + softmax ----
  {
    const int a = lane & 7;        // s = 4a + si
    const int fpart = lane >> 3;   // 0..7
    float accE[4][9];
#pragma unroll
    for (int si = 0; si < 4; ++si)
#pragma unroll
      for (int l = 0; l < 9; ++l) accE[si][l] = 0.f;
    for (int j = 0; j < 4; ++j) {
      int f = wave * 8 + fpart + 64 * j;
      float rr[12];
#pragma unroll
      for (int i = 0; i < 12; ++i) rr[i] = bf2f(qt[(4 * a + i) * QSTR + f]);
#pragma unroll
      for (int si = 0; si < 4; ++si) {
        float c = rr[si + 4];
#pragma unroll
        for (int l = 0; l < 9; ++l) accE[si][l] += c * rr[si + l];
      }
    }
#pragma unroll
    for (int off = 8; off < 64; off <<= 1)
#pragma unroll
      for (int si = 0; si < 4; ++si)
#pragma unroll
        for (int l = 0; l < 9; ++l) accE[si][l] += __shfl_xor(accE[si][l], off, 64);
    if (fpart == 0)
#pragma unroll
      for (int si = 0; si < 4; ++si)
#pragma unroll
        for (int l = 0; l < 9; ++l)
          part2[(wave * TS + 4 * a + si) * 9 + l] = accE[si][l];
  }
  __syncthreads();
  if (tid < TS) {
    float e[9];
#pragma unroll
    for (int l = 0; l < 9; ++l) {
      float s = 0.f;
#pragma unroll
      for (int w = 0; w < 8; ++w) s += part2[(w * TS + tid) * 9 + l];
      e[l] = s * (1.0f / 24.0f);
    }
    float m = e[0];
#pragma unroll
    for (int l = 1; l < 9; ++l) m = fmaxf(m, e[l]);
    float s = 0.f;
#pragma unroll
    for (int l = 0; l < 9; ++l) {
      e[l] = __expf(e[l] - m);
      s += e[l];
    }
    float inv = 1.0f / s;
#pragma unroll
    for (int l = 0; l < 9; ++l) ldsw[tid * 9 + l] = e[l] * inv;
  }
  __syncthreads();

  // ---- P3: pooled[s][e] = sum_l w[s][l] * xt[s+l][e]  (overlays qt) ----
  {
    const int s = tid & 31, ep = tid >> 5;  // ep 0..15, 16 e each
    float w9[9];
#pragma unroll
    for (int l = 0; l < 9; ++l) w9[l] = ldsw[s * 9 + l];
#pragma unroll
    for (int c = 0; c < 2; ++c) {
      int e8 = ep * 16 + c * 8;
      float o[8];
#pragma unroll
      for (int u = 0; u < 8; ++u) o[u] = 0.f;
#pragma unroll
      for (int l = 0; l < 9; ++l) {
        u16x8 xv = *(const u16x8*)&xt[(s + l) * XSTR + e8];
#pragma unroll
        for (int u = 0; u < 8; ++u) o[u] += w9[l] * bf2f(xv[u]);
      }
      u16x8 pv;
#pragma unroll
      for (int u = 0; u < 8; ++u) pv[u] = f2bf(o[u]);
      *(u16x8*)&pooled[s * PSTR + e8] = pv;
    }
  }
  __syncthreads();

  // ---- P4: K3 MFMA -> out[b][f][s]. Wave covers f-range wave*32, j<2. ----
  {
    const f32x4 zero = {0.f, 0.f, 0.f, 0.f};
    f32x4 acc[2][2];
#pragma unroll
    for (int i = 0; i < 2; ++i)
#pragma unroll
      for (int j = 0; j < 2; ++j) acc[i][j] = zero;
#pragma unroll
    for (int k0 = 0; k0 < 8; ++k0) {
      bf16x8 af[2], bf[2];
#pragma unroll
      for (int i = 0; i < 2; ++i)
        af[i] = *(const bf16x8*)&pooled[(i * 16 + lm) * PSTR + k0 * 32 + lk * 8];
#pragma unroll
      for (int j = 0; j < 2; ++j)
        bf[j] = *(const bf16x8*)&Wob[(size_t)(wave * 32 + j * 16 + lm) * E_DIM +
                                     k0 * 32 + lk * 8];
#pragma unroll
      for (int i = 0; i < 2; ++i)
#pragma unroll
        for (int j = 0; j < 2; ++j)
          acc[i][j] = __builtin_amdgcn_mfma_f32_16x16x32_bf16(af[i], bf[j], acc[i][j], 0, 0, 0);
    }
#pragma unroll
    for (int j = 0; j < 2; ++j) {
      int f = wave * 32 + j * 16 + lm;
      float bv = bo[f];
#pragma unroll
      for (int i = 0; i < 2; ++i) {
        int sl = i * 16 + lk * 4;
        float4 w = make_float4((acc[i][j][0] + bv) * (1.0f / 9.0f),
                               (acc[i][j][1] + bv) * (1.0f / 9.0f),
                               (acc[i][j][2] + bv) * (1.0f / 9.0f),
                               (acc[i][j][3] + bv) * (1.0f / 9.0f));
        *(float4*)&out[((size_t)b * E_DIM + f) * S_DIM + s0 + sl] = w;
      }
    }
  }
}

// ---------------------------------------------------------------------------
extern "C" void kernel_launch(void* const* d_in, const int* in_sizes, int n_in,
                              void* d_out, int out_size, void* d_ws, size_t ws_size,
                              hipStream_t stream) {
  const float* x = (const float*)d_in[0];
  const float* Wq = (const float*)d_in[1];
  const float* bq = (const float*)d_in[2];
  const float* Wo = (const float*)d_in[3];
  const float* bo = (const float*)d_in[4];
  float* out = (float*)d_out;

  u16* Wqb = (u16*)d_ws;
  u16* Wob = Wqb + 65536;

  convert_w<<<128, 256, 0, stream>>>(Wq, Wo, Wqb, Wob);
  fused_attn<<<dim3(S_DIM / TS, B_DIM), 512, 0, stream>>>(x, Wqb, bq, Wob, bo, out);
}